// Round 3
// baseline (23158.511 us; speedup 1.0000x reference)
//
#include <hip/hip_runtime.h>
#include <cstdint>
#include <cstddef>

// Problem constants
#define BB 32
#define TT 2048
#define DH 512
#define DIN 512
#define MM (BB * TT)   // 65536 rows for the input projection

typedef _Float16 half2_t __attribute__((ext_vector_type(2)));

__device__ __forceinline__ float fdot2(uint32_t w, uint32_t h, float acc) {
  return __builtin_amdgcn_fdot2(__builtin_bit_cast(half2_t, w),
                                __builtin_bit_cast(half2_t, h), acc, false);
}

__device__ __forceinline__ uint32_t pack_f16(float a, float b) {
  uint32_t lo = (uint32_t)__builtin_bit_cast(unsigned short, (_Float16)a);
  uint32_t hi = (uint32_t)__builtin_bit_cast(unsigned short, (_Float16)b);
  return lo | (hi << 16);
}

// ---------------------------------------------------------------------------
// Phase 1: out[m][n] = sum_k X[m][k] * Wih[k][n] + bias[n]   (fp32)
// M=65536, N=512, K=512. Tile 64x64, BK=16, 256 threads, 4x4 per thread.
// Writes into d_out (holds xw until the recurrence overwrites with h).
// ---------------------------------------------------------------------------
__global__ __launch_bounds__(256) void gemm_xw(
    const float* __restrict__ X, const float* __restrict__ W,
    const float* __restrict__ bias, float* __restrict__ out) {
  __shared__ float As[16][68];   // [k][m], padded
  __shared__ float Bs[16][68];   // [k][n], padded

  const int tid = threadIdx.x;
  const int m0 = blockIdx.x * 64;
  const int n0 = blockIdx.y * 64;
  const int tx = tid & 15;        // output col group
  const int ty = tid >> 4;        // output row group
  const int la_m = tid >> 2;          // A load: row within tile (0..63)
  const int la_k = (tid & 3) * 4;     // A load: 4 consecutive k
  const int lb_k = tid >> 4;          // B load: k row (0..15)
  const int lb_n = (tid & 15) * 4;    // B load: 4 consecutive n

  float acc[4][4] = {};

  for (int kb = 0; kb < DIN; kb += 16) {
    float4 av = *(const float4*)&X[(size_t)(m0 + la_m) * DIN + kb + la_k];
    float4 bv = *(const float4*)&W[(size_t)(kb + lb_k) * DH + n0 + lb_n];
    __syncthreads();
    As[la_k + 0][la_m] = av.x;
    As[la_k + 1][la_m] = av.y;
    As[la_k + 2][la_m] = av.z;
    As[la_k + 3][la_m] = av.w;
    *(float4*)&Bs[lb_k][lb_n] = bv;
    __syncthreads();
#pragma unroll
    for (int k = 0; k < 16; ++k) {
      float4 a4 = *(const float4*)&As[k][ty * 4];
      float4 b4 = *(const float4*)&Bs[k][tx * 4];
      float a[4] = {a4.x, a4.y, a4.z, a4.w};
      float b[4] = {b4.x, b4.y, b4.z, b4.w};
#pragma unroll
      for (int i = 0; i < 4; ++i)
#pragma unroll
        for (int j = 0; j < 4; ++j) acc[i][j] += a[i] * b[j];
    }
  }

  float4 bb = *(const float4*)&bias[n0 + tx * 4];
  float bba[4] = {bb.x, bb.y, bb.z, bb.w};
#pragma unroll
  for (int i = 0; i < 4; ++i) {
    float4 r;
    r.x = acc[i][0] + bba[0];
    r.y = acc[i][1] + bba[1];
    r.z = acc[i][2] + bba[2];
    r.w = acc[i][3] + bba[3];
    *(float4*)&out[(size_t)(m0 + ty * 4 + i) * DH + n0 + tx * 4] = r;
  }
}

// ---------------------------------------------------------------------------
// Phase 2: sequential recurrence, one block per batch chain, 512 threads
// (8 waves). k-split by wave: wave w covers k in [64w, 64w+64) (kp pairs
// [32w, 32w+32)). Thread (w,l) computes partial dots for 8 columns
// {l + 64c : c=0..7}: 6 columns from VGPR-resident W (192 VGPRs), 2 columns
// from LDS-resident W (128 KB, b128-friendly layout).
//
// amdgpu_waves_per_eu(2,2): ONLY 32 blocks exist on 256 CUs, so occupancy
// >1 block/CU is worthless — pin exactly 2 waves/EU so the allocator gets
// the full 256-VGPR budget and does NOT spill wr[] (round-2 failure mode:
// VGPR_Count=128 + 192 regs spilled to scratch -> 11 us/step).
//
// h distribution needs NO LDS: h[64w+l] lives in wave w lane l. Each step:
// DPP quad-perm pack (h[2i],h[2i+1]) into even lanes, then 32 v_readlane
// -> uniform SGPRs feed fdot2.
//
// Cross-wave reduction: partials P[8][512] f32 in LDS (conflict-free b32
// patterns), 2 barriers/step. xw read from io (= d_out), overwritten with h.
// ---------------------------------------------------------------------------
__global__ __attribute__((amdgpu_flat_work_group_size(512, 512),
                          amdgpu_waves_per_eu(2, 2)))
void rnn_rec(const float* __restrict__ Whh, float* __restrict__ io) {
  __shared__ uint4 WLI[16][512];   // 128 KB: per-thread 2 LDS columns of W
  __shared__ float P[8][512];      // 16 KB: cross-wave partials

  const int tid = threadIdx.x;
  const int w = tid >> 6;        // wave id: k-chunk owner
  const int l = tid & 63;        // lane
  const int b = blockIdx.x;      // batch
  const int kp0 = 32 * w;        // this wave's first k-pair

  // --- Load W slice into VGPRs: columns c=0..5, k-pairs kp0..kp0+32 ---
  uint32_t wr[6][32];
#pragma unroll
  for (int c = 0; c < 6; ++c) {
    const int col = l + 64 * c;
#pragma unroll 8
    for (int kp = 0; kp < 32; ++kp) {
      const int row = 2 * (kp0 + kp);
      wr[c][kp] = pack_f16(Whh[(size_t)row * DH + col],
                           Whh[(size_t)(row + 1) * DH + col]);
    }
  }

  // --- LDS W slice: columns c=6,7. WLI[i][tid] = 4 consecutive k-pairs of
  //     one column (i<8 -> col l+384, i>=8 -> col l+448). Lane-contiguous
  //     16B addresses -> conflict-free ds_read_b128.
  for (int i = 0; i < 16; ++i) {
    const int col = l + 64 * (6 + (i >> 3));
    const int kpb = kp0 + (i & 7) * 4;
    uint4 q;
    q.x = pack_f16(Whh[(size_t)(2 * kpb + 0) * DH + col], Whh[(size_t)(2 * kpb + 1) * DH + col]);
    q.y = pack_f16(Whh[(size_t)(2 * kpb + 2) * DH + col], Whh[(size_t)(2 * kpb + 3) * DH + col]);
    q.z = pack_f16(Whh[(size_t)(2 * kpb + 4) * DH + col], Whh[(size_t)(2 * kpb + 5) * DH + col]);
    q.w = pack_f16(Whh[(size_t)(2 * kpb + 6) * DH + col], Whh[(size_t)(2 * kpb + 7) * DH + col]);
    WLI[i][tid] = q;
  }
  __syncthreads();

  float* iop = io + (size_t)b * TT * DH + tid;
  float xw_cur = iop[0];
  float h = 0.f;   // h[tid] of previous step (h0 = 0)

  for (int t = 0; t < TT; ++t) {
    // Prefetch next timestep's xw (hides LLC/HBM latency under compute).
    float xw_next = 0.f;
    if (t + 1 < TT) xw_next = iop[(size_t)(t + 1) * DH];

    // Pack f16 pair (h[2i], h[2i+1]) into even lanes via DPP quad-perm swap.
    uint32_t hf = (uint32_t)__builtin_bit_cast(unsigned short, (_Float16)h);
    uint32_t nb = (uint32_t)__builtin_amdgcn_mov_dpp((int)hf, 0xB1, 0xF, 0xF, true);
    uint32_t pair = hf | (nb << 16);   // valid in even lanes

    // Broadcast this wave's 32 h-pairs to uniform registers (no LDS).
    uint32_t hps[32];
#pragma unroll
    for (int i = 0; i < 32; ++i)
      hps[i] = (uint32_t)__builtin_amdgcn_readlane((int)pair, 2 * i);

    // Partial dots: 6 register columns ...
    float acc[6] = {0.f, 0.f, 0.f, 0.f, 0.f, 0.f};
#pragma unroll
    for (int i = 0; i < 32; ++i) {
#pragma unroll
      for (int c = 0; c < 6; ++c) acc[c] = fdot2(wr[c][i], hps[i], acc[c]);
    }
    // ... and 2 LDS columns.
    float acc6 = 0.f, acc7 = 0.f;
#pragma unroll
    for (int i = 0; i < 8; ++i) {
      uint4 q = WLI[i][tid];
      acc6 = fdot2(q.x, hps[4 * i + 0], acc6);
      acc6 = fdot2(q.y, hps[4 * i + 1], acc6);
      acc6 = fdot2(q.z, hps[4 * i + 2], acc6);
      acc6 = fdot2(q.w, hps[4 * i + 3], acc6);
    }
#pragma unroll
    for (int i = 0; i < 8; ++i) {
      uint4 q = WLI[8 + i][tid];
      acc7 = fdot2(q.x, hps[4 * i + 0], acc7);
      acc7 = fdot2(q.y, hps[4 * i + 1], acc7);
      acc7 = fdot2(q.z, hps[4 * i + 2], acc7);
      acc7 = fdot2(q.w, hps[4 * i + 3], acc7);
    }

    // Publish partials (bank-conflict-free: bank = l % 32, 2-way).
#pragma unroll
    for (int c = 0; c < 6; ++c) P[w][l + 64 * c] = acc[c];
    P[w][l + 384] = acc6;
    P[w][l + 448] = acc7;
    __syncthreads();

    // Phase 2: thread tid finishes column tid.
    float s = xw_cur;
#pragma unroll
    for (int ww = 0; ww < 8; ++ww) s += P[ww][tid];
    float e = __expf(2.f * s);
    h = 1.f - 2.f / (e + 1.f);        // tanh(s)

    iop[(size_t)t * DH] = h;          // overwrite xw[t] with h_t
    xw_cur = xw_next;
    __syncthreads();                  // P reads done before next step's writes
  }
}

// ---------------------------------------------------------------------------
extern "C" void kernel_launch(void* const* d_in, const int* in_sizes, int n_in,
                              void* d_out, int out_size, void* d_ws, size_t ws_size,
                              hipStream_t stream) {
  const float* x    = (const float*)d_in[0];   // [32][2048][512]
  const float* Wih  = (const float*)d_in[1];   // [512][512]
  const float* Whh  = (const float*)d_in[2];   // [512][512]
  const float* bias = (const float*)d_in[3];   // [512]
  float* out = (float*)d_out;                  // [32][2048][512]
  (void)d_ws; (void)ws_size;                   // unused

  // xw = x @ W_ih + b  ->  written into d_out
  dim3 g1(MM / 64, DH / 64);
  gemm_xw<<<g1, 256, 0, stream>>>(x, Wih, bias, out);

  // Sequential recurrence, in-place over d_out (converts W_hh itself)
  rnn_rec<<<BB, 512, 0, stream>>>(Whh, out);
}

// Round 4
// 3554.240 us; speedup vs baseline: 6.5157x; 6.5157x over previous
//
#include <hip/hip_runtime.h>
#include <cstdint>
#include <cstddef>

// Problem constants
#define BB 32
#define TT 2048
#define DH 512
#define DIN 512
#define MM (BB * TT)   // 65536 rows for the input projection

typedef _Float16 half2_t __attribute__((ext_vector_type(2)));

__device__ __forceinline__ float fdot2(uint32_t w, uint32_t h, float acc) {
  return __builtin_amdgcn_fdot2(__builtin_bit_cast(half2_t, w),
                                __builtin_bit_cast(half2_t, h), acc, false);
}

__device__ __forceinline__ uint32_t pack_f16(float a, float b) {
  uint32_t lo = (uint32_t)__builtin_bit_cast(unsigned short, (_Float16)a);
  uint32_t hi = (uint32_t)__builtin_bit_cast(unsigned short, (_Float16)b);
  return lo | (hi << 16);
}

// ---------------------------------------------------------------------------
// Phase 1: out[m][n] = sum_k X[m][k] * Wih[k][n] + bias[n]   (fp32)
// M=65536, N=512, K=512. Tile 64x64, BK=16, 256 threads, 4x4 per thread.
// Writes into d_out (holds xw until the recurrence overwrites with h).
// ---------------------------------------------------------------------------
__global__ __launch_bounds__(256) void gemm_xw(
    const float* __restrict__ X, const float* __restrict__ W,
    const float* __restrict__ bias, float* __restrict__ out) {
  __shared__ float As[16][68];   // [k][m], padded
  __shared__ float Bs[16][68];   // [k][n], padded

  const int tid = threadIdx.x;
  const int m0 = blockIdx.x * 64;
  const int n0 = blockIdx.y * 64;
  const int tx = tid & 15;        // output col group
  const int ty = tid >> 4;        // output row group
  const int la_m = tid >> 2;          // A load: row within tile (0..63)
  const int la_k = (tid & 3) * 4;     // A load: 4 consecutive k
  const int lb_k = tid >> 4;          // B load: k row (0..15)
  const int lb_n = (tid & 15) * 4;    // B load: 4 consecutive n

  float acc[4][4] = {};

  for (int kb = 0; kb < DIN; kb += 16) {
    float4 av = *(const float4*)&X[(size_t)(m0 + la_m) * DIN + kb + la_k];
    float4 bv = *(const float4*)&W[(size_t)(kb + lb_k) * DH + n0 + lb_n];
    __syncthreads();
    As[la_k + 0][la_m] = av.x;
    As[la_k + 1][la_m] = av.y;
    As[la_k + 2][la_m] = av.z;
    As[la_k + 3][la_m] = av.w;
    *(float4*)&Bs[lb_k][lb_n] = bv;
    __syncthreads();
#pragma unroll
    for (int k = 0; k < 16; ++k) {
      float4 a4 = *(const float4*)&As[k][ty * 4];
      float4 b4 = *(const float4*)&Bs[k][tx * 4];
      float a[4] = {a4.x, a4.y, a4.z, a4.w};
      float b[4] = {b4.x, b4.y, b4.z, b4.w};
#pragma unroll
      for (int i = 0; i < 4; ++i)
#pragma unroll
        for (int j = 0; j < 4; ++j) acc[i][j] += a[i] * b[j];
    }
  }

  float4 bb = *(const float4*)&bias[n0 + tx * 4];
  float bba[4] = {bb.x, bb.y, bb.z, bb.w};
#pragma unroll
  for (int i = 0; i < 4; ++i) {
    float4 r;
    r.x = acc[i][0] + bba[0];
    r.y = acc[i][1] + bba[1];
    r.z = acc[i][2] + bba[2];
    r.w = acc[i][3] + bba[3];
    *(float4*)&out[(size_t)(m0 + ty * 4 + i) * DH + n0 + tx * 4] = r;
  }
}

// ---------------------------------------------------------------------------
// Phase 2: sequential recurrence, one block per batch chain, 512 threads
// (8 waves). k-split by wave: wave w covers k in [64w, 64w+64) (kp pairs
// [32w, 32w+32)). Thread (w,l) computes partial dots for 8 columns
// {l + 64c : c=0..7}: 6 columns from VGPR-resident W (192 VGPRs), 2 columns
// from LDS-resident W (128 KB, b128-friendly layout).
//
// CRITICAL (round-3 lesson, rule #20): every index into wr[][] must be a
// compile-time constant — a partially-unrolled load loop made wr scratch-
// allocated (localMem), and each step re-read 768 B/thread from scratch at
// ~137 cyc/load => 11 us/step. Both loops below are FULLY unrolled.
//
// amdgpu_waves_per_eu(2,2): only 32 blocks exist on 256 CUs, occupancy
// >1 block/CU is worthless; give the allocator the full 256-VGPR budget.
//
// h distribution needs NO LDS: h[64w+l] lives in wave w lane l. Each step:
// DPP quad-perm pack (h[2i],h[2i+1]) into even lanes, then 32 v_readlane
// -> uniform SGPRs feed fdot2.
//
// Cross-wave reduction: partials P[8][512] f32 in LDS (conflict-free b32
// patterns), 2 barriers/step. xw read from io (= d_out), overwritten with h.
// ---------------------------------------------------------------------------
__global__ __attribute__((amdgpu_flat_work_group_size(512, 512),
                          amdgpu_waves_per_eu(2, 2)))
void rnn_rec(const float* __restrict__ Whh, float* __restrict__ io) {
  __shared__ uint4 WLI[16][512];   // 128 KB: per-thread 2 LDS columns of W
  __shared__ float P[8][512];      // 16 KB: cross-wave partials

  const int tid = threadIdx.x;
  const int w = tid >> 6;        // wave id: k-chunk owner
  const int l = tid & 63;        // lane
  const int b = blockIdx.x;      // batch
  const int kp0 = 32 * w;        // this wave's first k-pair

  // --- Load W slice into VGPRs: columns c=0..5, k-pairs kp0..kp0+32.
  //     FULL unroll: all wr indices static -> stays in registers.
  uint32_t wr[6][32];
#pragma unroll
  for (int c = 0; c < 6; ++c) {
    const int col = l + 64 * c;
    const float* wp = Whh + (size_t)(2 * kp0) * DH + col;
#pragma unroll
    for (int kp = 0; kp < 32; ++kp) {
      wr[c][kp] = pack_f16(wp[(size_t)(2 * kp) * DH],
                           wp[(size_t)(2 * kp + 1) * DH]);
    }
  }

  // --- LDS W slice: columns c=6,7. WLI[i][tid] = 4 consecutive k-pairs of
  //     one column (i<8 -> col l+384, i>=8 -> col l+448). Lane-contiguous
  //     16B addresses -> conflict-free ds_read_b128.
  for (int i = 0; i < 16; ++i) {
    const int col = l + 64 * (6 + (i >> 3));
    const int kpb = kp0 + (i & 7) * 4;
    uint4 q;
    q.x = pack_f16(Whh[(size_t)(2 * kpb + 0) * DH + col], Whh[(size_t)(2 * kpb + 1) * DH + col]);
    q.y = pack_f16(Whh[(size_t)(2 * kpb + 2) * DH + col], Whh[(size_t)(2 * kpb + 3) * DH + col]);
    q.z = pack_f16(Whh[(size_t)(2 * kpb + 4) * DH + col], Whh[(size_t)(2 * kpb + 5) * DH + col]);
    q.w = pack_f16(Whh[(size_t)(2 * kpb + 6) * DH + col], Whh[(size_t)(2 * kpb + 7) * DH + col]);
    WLI[i][tid] = q;
  }
  __syncthreads();

  float* iop = io + (size_t)b * TT * DH + tid;
  float xw_cur = iop[0];
  float h = 0.f;   // h[tid] of previous step (h0 = 0)

  for (int t = 0; t < TT; ++t) {
    // Prefetch next timestep's xw (issued early; completes by the barrier).
    float xw_next = 0.f;
    if (t + 1 < TT) xw_next = iop[(size_t)(t + 1) * DH];

    // Pack f16 pair (h[2i], h[2i+1]) into even lanes via DPP quad-perm swap.
    uint32_t hf = (uint32_t)__builtin_bit_cast(unsigned short, (_Float16)h);
    uint32_t nb = (uint32_t)__builtin_amdgcn_mov_dpp((int)hf, 0xB1, 0xF, 0xF, true);
    uint32_t pair = hf | (nb << 16);   // valid in even lanes

    // Broadcast this wave's 32 h-pairs to uniform registers (no LDS).
    uint32_t hps[32];
#pragma unroll
    for (int i = 0; i < 32; ++i)
      hps[i] = (uint32_t)__builtin_amdgcn_readlane((int)pair, 2 * i);

    // Partial dots: 6 register columns ...
    float acc[6] = {0.f, 0.f, 0.f, 0.f, 0.f, 0.f};
#pragma unroll
    for (int i = 0; i < 32; ++i) {
#pragma unroll
      for (int c = 0; c < 6; ++c) acc[c] = fdot2(wr[c][i], hps[i], acc[c]);
    }
    // ... and 2 LDS columns.
    float acc6 = 0.f, acc7 = 0.f;
#pragma unroll
    for (int i = 0; i < 8; ++i) {
      uint4 q = WLI[i][tid];
      acc6 = fdot2(q.x, hps[4 * i + 0], acc6);
      acc6 = fdot2(q.y, hps[4 * i + 1], acc6);
      acc6 = fdot2(q.z, hps[4 * i + 2], acc6);
      acc6 = fdot2(q.w, hps[4 * i + 3], acc6);
    }
#pragma unroll
    for (int i = 0; i < 8; ++i) {
      uint4 q = WLI[8 + i][tid];
      acc7 = fdot2(q.x, hps[4 * i + 0], acc7);
      acc7 = fdot2(q.y, hps[4 * i + 1], acc7);
      acc7 = fdot2(q.z, hps[4 * i + 2], acc7);
      acc7 = fdot2(q.w, hps[4 * i + 3], acc7);
    }

    // Publish partials (bank-conflict-free: bank = l % 32, 2-way).
#pragma unroll
    for (int c = 0; c < 6; ++c) P[w][l + 64 * c] = acc[c];
    P[w][l + 384] = acc6;
    P[w][l + 448] = acc7;
    __syncthreads();

    // Phase 2: thread tid finishes column tid.
    float s = xw_cur;
#pragma unroll
    for (int ww = 0; ww < 8; ++ww) s += P[ww][tid];
    float e = __expf(2.f * s);
    h = 1.f - 2.f / (e + 1.f);        // tanh(s)

    iop[(size_t)t * DH] = h;          // overwrite xw[t] with h_t
    xw_cur = xw_next;
    __syncthreads();                  // P reads done before next step's writes
  }
}

// ---------------------------------------------------------------------------
extern "C" void kernel_launch(void* const* d_in, const int* in_sizes, int n_in,
                              void* d_out, int out_size, void* d_ws, size_t ws_size,
                              hipStream_t stream) {
  const float* x    = (const float*)d_in[0];   // [32][2048][512]
  const float* Wih  = (const float*)d_in[1];   // [512][512]
  const float* Whh  = (const float*)d_in[2];   // [512][512]
  const float* bias = (const float*)d_in[3];   // [512]
  float* out = (float*)d_out;                  // [32][2048][512]
  (void)d_ws; (void)ws_size;                   // unused

  // xw = x @ W_ih + b  ->  written into d_out
  dim3 g1(MM / 64, DH / 64);
  gemm_xw<<<g1, 256, 0, stream>>>(x, Wih, bias, out);

  // Sequential recurrence, in-place over d_out (converts W_hh itself)
  rnn_rec<<<BB, 512, 0, stream>>>(Whh, out);
}